// Round 1
// baseline (938.815 us; speedup 1.0000x reference)
//
#include <hip/hip_runtime.h>
#include <math.h>

// dims
#define NB 32
#define CC 64
#define TT 256
#define VV 25
#define HH 8
#define HDD 8
#define OO 64
#define BB (NB*TT)          // 8192 blocks
#define TV (TT*VV)          // 6400
#define SCALE 0.35355339059327373f
#define EPSV 1e-5f

// LDS pitches
#define FP 68   // feat / yn / z rows of 64, float4-aligned, banks rotate by 4
#define QP 129  // qk rows of 128, odd pitch -> lane-strided b32 conflict-free
#define WP 65   // wst rows of 64 (o-minor), odd pitch

__global__ __launch_bounds__(256, 3)
void sagc_kernel(const float* __restrict__ x,
                 const float* __restrict__ ln_g, const float* __restrict__ ln_b,
                 const float* __restrict__ w_qk, const float* __restrict__ b_qk,
                 const float* __restrict__ topo,
                 const float* __restrict__ conv_w, const float* __restrict__ conv_b,
                 const float* __restrict__ bn_g, const float* __restrict__ bn_b,
                 const float* __restrict__ bn_m, const float* __restrict__ bn_v,
                 float* __restrict__ out)
{
    __shared__ float feat_s[VV*FP];     // raw x tile [v][c]
    __shared__ float zs[VV*FP];         // yn -> z -> staged output (union)
    __shared__ float wqk_s[OO*WP];      // qk[25][QP] -> wst[c][o] (union, 4160 floats)
    __shared__ float A_s[HH*VV*VV];     // dots -> gated attention

    const int tid = threadIdx.x;
    const int b = blockIdx.x;
    const int n = b / TT, t = b - n*TT;
    const float* xb = x + (size_t)n*(CC*TV) + (size_t)t*VV;  // + c*TV + v

    // ---- phase 0: load x tile -> feat_s[v][c] (coalesced 25-float rows) ----
    for (int i = tid; i < VV*CC; i += 256) {
        int c = i / VV, v = i - c*VV;
        feat_s[v*FP + c] = xb[c*TV + v];
    }
    __syncthreads();

    // ---- phase 1: LayerNorm over C -> zs (as yn) ----
    {
        const int lane = tid & 63, wv = tid >> 6;
        const float g = ln_g[lane], bt = ln_b[lane];
        for (int v = wv; v < VV; v += 4) {
            float f = feat_s[v*FP + lane];
            float s = f, sq = f*f;
            #pragma unroll
            for (int off = 32; off > 0; off >>= 1) {
                s  += __shfl_xor(s, off, 64);
                sq += __shfl_xor(sq, off, 64);
            }
            float mu  = s * (1.0f/64.0f);
            float var = sq * (1.0f/64.0f) - mu*mu;
            float rs  = rsqrtf(var + EPSV);
            zs[v*FP + lane] = (f - mu)*rs*g + bt;
        }
    }
    __syncthreads();

    // ---- phase 2: qk = yn @ w_qk + b_qk -> wqk_s[v][j], pitch QP ----
    {
        const int j = tid & 127, vg = tid >> 7;   // wave-uniform vg
        float acc[13];
        #pragma unroll
        for (int i = 0; i < 13; i++) acc[i] = 0.f;
        for (int cq = 0; cq < CC; cq += 4) {
            float w0 = w_qk[(cq+0)*128 + j];
            float w1 = w_qk[(cq+1)*128 + j];
            float w2 = w_qk[(cq+2)*128 + j];
            float w3 = w_qk[(cq+3)*128 + j];
            #pragma unroll
            for (int i = 0; i < 13; i++) {
                int v = vg + 2*i;
                if (v < VV) {
                    const float4 y4 = *(const float4*)&zs[v*FP + cq];  // broadcast b128
                    acc[i] += y4.x*w0 + y4.y*w1 + y4.z*w2 + y4.w*w3;
                }
            }
        }
        const float bq = b_qk[j];
        #pragma unroll
        for (int i = 0; i < 13; i++) {
            int v = vg + 2*i;
            if (v < VV) wqk_s[v*QP + j] = acc[i] + bq;
        }
    }
    __syncthreads();

    // ---- phase 3: dots[h][u][v] = SCALE * q.k ----
    for (int idx = tid; idx < HH*VV*VV; idx += 256) {
        int h = idx / (VV*VV);
        int r = idx - h*(VV*VV);
        int u = r / VV, v = r - u*VV;
        const float* qrow = &wqk_s[u*QP + h*HDD];        // broadcast within v-run
        const float* krow = &wqk_s[v*QP + 64 + h*HDD];   // lane-strided, odd pitch
        float d = 0.f;
        #pragma unroll
        for (int i = 0; i < HDD; i++) d += qrow[i]*krow[i];
        A_s[idx] = d * SCALE;
    }
    __syncthreads();

    // ---- phase 4: softmax over v, then * topology ----
    if (tid < HH*VV) {
        int h = tid / VV, u = tid - h*VV;
        float* row = &A_s[h*(VV*VV) + u*VV];
        const float* trow = &topo[h*(VV*VV) + u*VV];
        float m = -1e30f;
        #pragma unroll
        for (int v = 0; v < VV; v++) m = fmaxf(m, row[v]);
        float e[VV]; float s = 0.f;
        #pragma unroll
        for (int v = 0; v < VV; v++) { e[v] = __expf(row[v] - m); s += e[v]; }
        float inv = 1.0f / s;
        #pragma unroll
        for (int v = 0; v < VV; v++) row[v] = e[v]*inv*trow[v];
    }
    // loop-top sync of h=0 covers the A_s hazard

    // ---- phase 5: per-head z = A.feat, out += z @ conv_w[h]^T ----
    const int o  = tid & 63, ug = tid >> 6;           // accumulate mapping (wave-uniform ug)
    const int cq = (tid & 15) * 4, zg = tid >> 4;     // z mapping
    float acc[7];
    #pragma unroll
    for (int i = 0; i < 7; i++) acc[i] = 0.f;

    for (int h = 0; h < HH; h++) {
        __syncthreads();   // previous accumulate readers done (and softmax for h=0)
        // stage conv_w[h][o][c] -> wst[c][o] (conflict-free writes, odd pitch)
        const float* cw = conv_w + h*(OO*CC);
        for (int i = tid; i < OO*CC; i += 256) {
            wqk_s[(i & 63)*WP + (i >> 6)] = cw[i];
        }
        // z[u][cq..cq+3] = sum_v A[h][u][v] * feat[v][cq..cq+3]
        const float* Ah = &A_s[h*(VV*VV)];
        float z0x=0,z0y=0,z0z=0,z0w=0, z1x=0,z1y=0,z1z=0,z1w=0;
        for (int v = 0; v < VV; v++) {
            const float4 f4 = *(const float4*)&feat_s[v*FP + cq];
            const float a0 = Ah[zg*VV + v];
            z0x += a0*f4.x; z0y += a0*f4.y; z0z += a0*f4.z; z0w += a0*f4.w;
            if (zg < 9) {
                const float a1 = Ah[(zg+16)*VV + v];
                z1x += a1*f4.x; z1y += a1*f4.y; z1z += a1*f4.z; z1w += a1*f4.w;
            }
        }
        *(float4*)&zs[zg*FP + cq] = make_float4(z0x,z0y,z0z,z0w);
        if (zg < 9) *(float4*)&zs[(zg+16)*FP + cq] = make_float4(z1x,z1y,z1z,z1w);
        __syncthreads();
        // acc[u][o] += sum_c z[u][c]*wst[c][o]
        for (int c = 0; c < CC; c += 4) {
            float w0 = wqk_s[(c+0)*WP + o];
            float w1 = wqk_s[(c+1)*WP + o];
            float w2 = wqk_s[(c+2)*WP + o];
            float w3 = wqk_s[(c+3)*WP + o];
            #pragma unroll
            for (int iu = 0; iu < 7; iu++) {
                int u = ug + 4*iu;
                if (u < VV) {
                    const float4 z4 = *(const float4*)&zs[u*FP + c];  // broadcast b128
                    acc[iu] += z4.x*w0 + z4.y*w1 + z4.z*w2 + z4.w*w3;
                }
            }
        }
    }
    __syncthreads();

    // ---- epilogue: conv_b sum + BN, stage outs[o][u] ----
    {
        const float gv = bn_g[o] * rsqrtf(bn_v[o] + EPSV);
        const float bv = bn_b[o] - bn_m[o]*gv;
        float cb = 0.f;
        #pragma unroll
        for (int h = 0; h < HH; h++) cb += conv_b[h*OO + o];
        #pragma unroll
        for (int iu = 0; iu < 7; iu++) {
            int u = ug + 4*iu;
            if (u < VV) zs[o*VV + u] = (acc[iu] + cb)*gv + bv;
        }
    }
    __syncthreads();

    // ---- residual + ReLU, coalesced store ----
    float* ob = out + (size_t)n*(CC*TV) + (size_t)t*VV;
    for (int i = tid; i < VV*CC; i += 256) {
        int c = i / VV, v = i - c*VV;
        ob[c*TV + v] = fmaxf(zs[c*VV + v] + xb[c*TV + v], 0.f);
    }
}

extern "C" void kernel_launch(void* const* d_in, const int* in_sizes, int n_in,
                              void* d_out, int out_size, void* d_ws, size_t ws_size,
                              hipStream_t stream) {
    const float* x      = (const float*)d_in[0];
    const float* ln_g   = (const float*)d_in[1];
    const float* ln_b   = (const float*)d_in[2];
    const float* w_qk   = (const float*)d_in[3];
    const float* b_qk   = (const float*)d_in[4];
    const float* topo   = (const float*)d_in[5];
    const float* conv_w = (const float*)d_in[6];
    const float* conv_b = (const float*)d_in[7];
    const float* bn_g   = (const float*)d_in[8];
    const float* bn_b   = (const float*)d_in[9];
    const float* bn_m   = (const float*)d_in[10];
    const float* bn_v   = (const float*)d_in[11];
    float* outp = (float*)d_out;

    hipLaunchKernelGGL(sagc_kernel, dim3(BB), dim3(256), 0, stream,
                       x, ln_g, ln_b, w_qk, b_qk, topo, conv_w, conv_b,
                       bn_g, bn_b, bn_m, bn_v, outp);
}

// Round 2
// 344.092 us; speedup vs baseline: 2.7284x; 2.7284x over previous
//
#include <hip/hip_runtime.h>
#include <math.h>

#define TT 256
#define TV 6400
#define SCALE 0.35355339059327373f
#define EPSV 1e-5f

typedef __attribute__((ext_vector_type(8))) short bf16x8;
typedef __attribute__((ext_vector_type(4))) float f32x4;

__device__ __forceinline__ unsigned short f2bf(float f) {
    union { float f; unsigned int u; } v; v.f = f;
    unsigned int r = v.u + 0x7fffu + ((v.u >> 16) & 1u);
    return (unsigned short)(r >> 16);
}
__device__ __forceinline__ float bf2f(short s) {
    union { unsigned int u; float f; } v;
    v.u = ((unsigned int)(unsigned short)s) << 16;
    return v.f;
}

// ---- prep: swizzle w_qk and conv_w into MFMA B-fragment order (bf16) in ws ----
// wqk_f : 16 frags (nt in 0..7, ks in 0..1), frag = 512 ushort: [lane][j]
//         value = w_qk[(ks*32 + (lane>>4)*8 + j)*128 + nt*16 + (lane&15)]
// wcv_f : 64 frags (ot in 0..3, ks in 0..15):
//         k = ks*32 + (lane>>4)*8 + j; h=k>>6; c=k&63; o = ot*16 + (lane&15)
//         value = conv_w[h*4096 + o*64 + c]
__global__ void prep_kernel(const float* __restrict__ w_qk,
                            const float* __restrict__ conv_w,
                            unsigned short* __restrict__ ws) {
    int i = blockIdx.x * 256 + threadIdx.x;   // grid covers 40960 exactly
    if (i < 8192) {
        int f = i >> 9, rem = i & 511, l = rem >> 3, j = rem & 7;
        int nt = f >> 1, ks = f & 1;
        int k = ks * 32 + (l >> 4) * 8 + j;
        int n = nt * 16 + (l & 15);
        ws[i] = f2bf(w_qk[k * 128 + n]);
    } else {
        int i2 = i - 8192;
        int g = i2 >> 9, rem = i2 & 511, l = rem >> 3, j = rem & 7;
        int ot = g >> 4, ks = g & 15;
        int k = ks * 32 + (l >> 4) * 8 + j;
        int h = k >> 6, c = k & 63;
        int o = ot * 16 + (l & 15);
        ws[8192 + i2] = f2bf(conv_w[h * 4096 + o * 64 + c]);
    }
}

// LDS layout (bytes), unions chosen so no live ranges overlap:
//   [0     , 16384) G    bf16 [8][32][32]  (raw dots -> gated attn; also xs fp32 [25][68] early)
//   [16384 , 49664) Zbig bf16 [32][520]    (also yn bf16 [25][72] early)
//   [49664 , 56464) qkb  bf16 [25][136]    (also outs fp32 [64][26] late)
//   [56464 , 62608) featT bf16 [64][48]    (x transposed, v-pad zeroed)
__global__ __launch_bounds__(256, 2)
void sagc_kernel(const float* __restrict__ x,
                 const float* __restrict__ ln_g, const float* __restrict__ ln_b,
                 const float* __restrict__ b_qk,
                 const float* __restrict__ topo,
                 const float* __restrict__ conv_b,
                 const float* __restrict__ bn_g, const float* __restrict__ bn_b,
                 const float* __restrict__ bn_m, const float* __restrict__ bn_v,
                 const unsigned short* __restrict__ ws,
                 float* __restrict__ out)
{
    __shared__ __align__(16) unsigned char smem[62608];
    float*          xs  = (float*)smem;                       // [25][68]
    unsigned short* G   = (unsigned short*)smem;              // [8][32][32]
    unsigned short* yn  = (unsigned short*)(smem + 16384);    // [25][72]
    unsigned short* Zb  = (unsigned short*)(smem + 16384);    // [32][520]
    unsigned short* qkb = (unsigned short*)(smem + 49664);    // [25][136]
    float*          outs= (float*)(smem + 49664);             // [64][26]
    unsigned short* fT  = (unsigned short*)(smem + 56464);    // [64][48]

    const unsigned short* wqk_f = ws;          // 8192
    const unsigned short* wcv_f = ws + 8192;   // 32768

    const int tid = threadIdx.x;
    const int b = blockIdx.x;
    const int n = b / TT, t = b - n * TT;
    const float* xb = x + (size_t)n * (64 * TV) + (size_t)t * 25;  // + c*TV + v

    const int lane = tid & 63, wv = tid >> 6;
    const int l15 = lane & 15, quad = lane >> 4;

    // ---- phase 0: load x -> xs fp32 [v][c], featT bf16 [c][v] (pad v=25..31 zero) ----
    for (int i = tid; i < 1600; i += 256) {
        int c = i / 25, v = i - c * 25;
        float val = xb[c * TV + v];
        xs[v * 68 + c] = val;
        fT[c * 48 + v] = f2bf(val);
    }
    for (int i = tid; i < 448; i += 256) {
        int c = i / 7, v = 25 + (i % 7);
        fT[c * 48 + v] = 0;
    }
    __syncthreads();

    // ---- phase 1: LayerNorm over C -> yn bf16 [v][72] ----
    {
        const float g = ln_g[lane], bt = ln_b[lane];
        for (int v = wv; v < 25; v += 4) {
            float f = xs[v * 68 + lane];
            float s = f, sq = f * f;
            #pragma unroll
            for (int off = 32; off > 0; off >>= 1) {
                s  += __shfl_xor(s, off, 64);
                sq += __shfl_xor(sq, off, 64);
            }
            float mu = s * (1.0f / 64.0f);
            float var = sq * (1.0f / 64.0f) - mu * mu;
            float rs = rsqrtf(var + EPSV);
            yn[v * 72 + lane] = f2bf((f - mu) * rs * g + bt);
        }
    }
    __syncthreads();

    // ---- phase 2: qk = yn @ w_qk + b_qk  (MFMA, M=25pad32, N=128, K=64) ----
    {
        bf16x8 a[2][2];
        #pragma unroll
        for (int mt = 0; mt < 2; mt++)
            #pragma unroll
            for (int ks = 0; ks < 2; ks++)
                a[mt][ks] = *(const bf16x8*)&yn[(mt * 16 + l15) * 72 + ks * 32 + quad * 8];
        #pragma unroll
        for (int i = 0; i < 2; i++) {
            int nt = wv * 2 + i;
            f32x4 acc0 = {0.f, 0.f, 0.f, 0.f};
            f32x4 acc1 = {0.f, 0.f, 0.f, 0.f};
            #pragma unroll
            for (int ks = 0; ks < 2; ks++) {
                bf16x8 bf = *(const bf16x8*)&wqk_f[(nt * 2 + ks) * 512 + lane * 8];
                acc0 = __builtin_amdgcn_mfma_f32_16x16x32_bf16(a[0][ks], bf, acc0, 0, 0, 0);
                acc1 = __builtin_amdgcn_mfma_f32_16x16x32_bf16(a[1][ks], bf, acc1, 0, 0, 0);
            }
            float bq = b_qk[nt * 16 + l15];
            #pragma unroll
            for (int r = 0; r < 4; r++) {
                int u0 = quad * 4 + r;
                qkb[u0 * 136 + nt * 16 + l15] = f2bf(acc0[r] + bq);
                int u1 = 16 + u0;
                if (u1 < 25) qkb[u1 * 136 + nt * 16 + l15] = f2bf(acc1[r] + bq);
            }
        }
    }
    __syncthreads();

    // ---- phase 3: dots[h][u][v] (VALU, bf16 in/out) -> G ----
    for (int idx = tid; idx < 5000; idx += 256) {
        int h = idx / 625;
        int r = idx - h * 625;
        int u = r / 25, v = r - u * 25;
        const bf16x8 q8 = *(const bf16x8*)&qkb[u * 136 + h * 8];
        const bf16x8 k8 = *(const bf16x8*)&qkb[v * 136 + 64 + h * 8];
        float d = 0.f;
        #pragma unroll
        for (int i = 0; i < 8; i++) d += bf2f(q8[i]) * bf2f(k8[i]);
        G[h * 1024 + u * 32 + v] = f2bf(d * SCALE);
    }
    __syncthreads();

    // ---- phase 4: softmax over v, * topo, zero v-pad -> G bf16 ----
    if (tid < 200) {
        int h = tid / 25, u = tid - h * 25;
        unsigned short* row = &G[h * 1024 + u * 32];
        const float* trow = &topo[h * 625 + u * 25];
        float e[25]; float m = -1e30f;
        #pragma unroll
        for (int v = 0; v < 25; v++) { e[v] = bf2f((short)row[v]); m = fmaxf(m, e[v]); }
        float s = 0.f;
        #pragma unroll
        for (int v = 0; v < 25; v++) { e[v] = __expf(e[v] - m); s += e[v]; }
        float inv = 1.0f / s;
        #pragma unroll
        for (int v = 0; v < 25; v++) row[v] = f2bf(e[v] * inv * trow[v]);
        #pragma unroll
        for (int v = 25; v < 32; v++) row[v] = 0;
    }
    __syncthreads();

    // ---- phase 5: z_h = G_h @ feat (MFMA, per-wave 2 heads) -> Zbig bf16 [u][h*64+c] ----
    {
        bf16x8 bfr[4];
        #pragma unroll
        for (int nt = 0; nt < 4; nt++)
            bfr[nt] = *(const bf16x8*)&fT[(nt * 16 + l15) * 48 + quad * 8];
        #pragma unroll
        for (int hh = 0; hh < 2; hh++) {
            int h = wv * 2 + hh;
            bf16x8 a0 = *(const bf16x8*)&G[h * 1024 + l15 * 32 + quad * 8];
            bf16x8 a1 = *(const bf16x8*)&G[h * 1024 + (16 + l15) * 32 + quad * 8];
            #pragma unroll
            for (int nt = 0; nt < 4; nt++) {
                f32x4 d0 = {0.f, 0.f, 0.f, 0.f};
                f32x4 d1 = {0.f, 0.f, 0.f, 0.f};
                d0 = __builtin_amdgcn_mfma_f32_16x16x32_bf16(a0, bfr[nt], d0, 0, 0, 0);
                d1 = __builtin_amdgcn_mfma_f32_16x16x32_bf16(a1, bfr[nt], d1, 0, 0, 0);
                #pragma unroll
                for (int r = 0; r < 4; r++) {
                    int u0 = quad * 4 + r;
                    Zb[u0 * 520 + h * 64 + nt * 16 + l15] = f2bf(d0[r]);
                    int u1 = 16 + u0;
                    if (u1 < 25) Zb[u1 * 520 + h * 64 + nt * 16 + l15] = f2bf(d1[r]);
                }
            }
        }
    }
    __syncthreads();

    // ---- phase 6: out = Zbig[25pad32 x 512] @ W2[512 x 64] (MFMA) + BN -> outs ----
    {
        const int ot = wv;
        f32x4 acc0 = {0.f, 0.f, 0.f, 0.f};
        f32x4 acc1 = {0.f, 0.f, 0.f, 0.f};
        #pragma unroll 4
        for (int ks = 0; ks < 16; ks++) {
            bf16x8 bfr = *(const bf16x8*)&wcv_f[(ot * 16 + ks) * 512 + lane * 8];
            bf16x8 a0 = *(const bf16x8*)&Zb[l15 * 520 + ks * 32 + quad * 8];
            bf16x8 a1 = *(const bf16x8*)&Zb[(16 + l15) * 520 + ks * 32 + quad * 8];
            acc0 = __builtin_amdgcn_mfma_f32_16x16x32_bf16(a0, bfr, acc0, 0, 0, 0);
            acc1 = __builtin_amdgcn_mfma_f32_16x16x32_bf16(a1, bfr, acc1, 0, 0, 0);
        }
        int o = ot * 16 + l15;
        float gg = bn_g[o] * rsqrtf(bn_v[o] + EPSV);
        float bb = bn_b[o] - bn_m[o] * gg;
        float cb = 0.f;
        #pragma unroll
        for (int h = 0; h < 8; h++) cb += conv_b[h * 64 + o];
        #pragma unroll
        for (int r = 0; r < 4; r++) {
            int u0 = quad * 4 + r;
            outs[o * 26 + u0] = (acc0[r] + cb) * gg + bb;
            int u1 = 16 + u0;
            if (u1 < 25) outs[o * 26 + u1] = (acc1[r] + cb) * gg + bb;
        }
    }
    __syncthreads();

    // ---- phase 7: residual + ReLU, coalesced store ----
    float* ob = out + (size_t)n * (64 * TV) + (size_t)t * 25;
    for (int i = tid; i < 1600; i += 256) {
        int o = i / 25, v = i - o * 25;
        float val = outs[o * 26 + v] + xb[o * TV + v];
        ob[o * TV + v] = fmaxf(val, 0.f);
    }
}

extern "C" void kernel_launch(void* const* d_in, const int* in_sizes, int n_in,
                              void* d_out, int out_size, void* d_ws, size_t ws_size,
                              hipStream_t stream) {
    const float* x      = (const float*)d_in[0];
    const float* ln_g   = (const float*)d_in[1];
    const float* ln_b   = (const float*)d_in[2];
    const float* w_qk   = (const float*)d_in[3];
    const float* b_qk   = (const float*)d_in[4];
    const float* topo   = (const float*)d_in[5];
    const float* conv_w = (const float*)d_in[6];
    const float* conv_b = (const float*)d_in[7];
    const float* bn_g   = (const float*)d_in[8];
    const float* bn_b   = (const float*)d_in[9];
    const float* bn_m   = (const float*)d_in[10];
    const float* bn_v   = (const float*)d_in[11];
    float* outp = (float*)d_out;
    unsigned short* wsp = (unsigned short*)d_ws;

    hipLaunchKernelGGL(prep_kernel, dim3(160), dim3(256), 0, stream, w_qk, conv_w, wsp);
    hipLaunchKernelGGL(sagc_kernel, dim3(8192), dim3(256), 0, stream,
                       x, ln_g, ln_b, b_qk, topo, conv_b, bn_g, bn_b, bn_m, bn_v,
                       (const unsigned short*)wsp, outp);
}

// Round 3
// 273.884 us; speedup vs baseline: 3.4278x; 1.2563x over previous
//
#include <hip/hip_runtime.h>
#include <math.h>

#define TT 256
#define TV 6400
#define SCALE 0.35355339059327373f
#define EPSV 1e-5f

typedef __attribute__((ext_vector_type(8))) short bf16x8;
typedef __attribute__((ext_vector_type(4))) float f32x4;
typedef __attribute__((ext_vector_type(16))) float f32x16;

__device__ __forceinline__ unsigned short f2bf(float f) {
    union { float f; unsigned int u; } v; v.f = f;
    unsigned int r = v.u + 0x7fffu + ((v.u >> 16) & 1u);
    return (unsigned short)(r >> 16);
}
__device__ __forceinline__ float bf2f(short s) {
    union { unsigned int u; float f; } v;
    v.u = ((unsigned int)(unsigned short)s) << 16;
    return v.f;
}

// ---- prep: swizzle w_qk and conv_w into MFMA B-fragment order (bf16) in ws ----
__global__ void prep_kernel(const float* __restrict__ w_qk,
                            const float* __restrict__ conv_w,
                            unsigned short* __restrict__ ws) {
    int i = blockIdx.x * 256 + threadIdx.x;   // grid covers 40960 exactly
    if (i < 8192) {
        int f = i >> 9, rem = i & 511, l = rem >> 3, j = rem & 7;
        int nt = f >> 1, ks = f & 1;
        int k = ks * 32 + (l >> 4) * 8 + j;
        int n = nt * 16 + (l & 15);
        ws[i] = f2bf(w_qk[k * 128 + n]);
    } else {
        int i2 = i - 8192;
        int g = i2 >> 9, rem = i2 & 511, l = rem >> 3, j = rem & 7;
        int ot = g >> 4, ks = g & 15;
        int k = ks * 32 + (l >> 4) * 8 + j;
        int h = k >> 6, c = k & 63;
        int o = ot * 16 + (l & 15);
        ws[8192 + i2] = f2bf(conv_w[h * 4096 + o * 64 + c]);
    }
}

// LDS regions (44 KB total -> 3 blocks/CU):
//  [0     ,16384) G  bf16 [8][32][32]   (xs fp32 [25][68] lives here early)
//  [16384 ,32768) Zh bf16 [32][256] swz (yn bf16 [25->32][64] swz early; outs fp32 [64][26] late)
//  [32768 ,40960) qkb bf16 [32][128] swz
//  [40960 ,45056) fT bf16 [64][32]
__global__ __launch_bounds__(256, 3)
void sagc_kernel(const float* __restrict__ x,
                 const float* __restrict__ ln_g, const float* __restrict__ ln_b,
                 const float* __restrict__ b_qk,
                 const float* __restrict__ topo,
                 const float* __restrict__ conv_b,
                 const float* __restrict__ bn_g, const float* __restrict__ bn_b,
                 const float* __restrict__ bn_m, const float* __restrict__ bn_v,
                 const unsigned short* __restrict__ ws,
                 float* __restrict__ out)
{
    __shared__ __align__(16) unsigned char smem[45056];
    float*          xs  = (float*)smem;                       // [25][68]
    unsigned short* G   = (unsigned short*)smem;              // [8][32][32]
    unsigned short* yn  = (unsigned short*)(smem + 16384);    // [25][64] swizzled
    unsigned short* Zh  = (unsigned short*)(smem + 16384);    // [32][256] swizzled
    float*          outs= (float*)(smem + 16384);             // [64][26]
    unsigned short* qkb = (unsigned short*)(smem + 32768);    // [32][128] swizzled
    unsigned short* fT  = (unsigned short*)(smem + 40960);    // [64][32]

    const unsigned short* wqk_f = ws;          // 8192
    const unsigned short* wcv_f = ws + 8192;   // 32768

    const int tid = threadIdx.x;
    const int b = blockIdx.x;
    const int n = b / TT, t = b - n * TT;
    const float* xb = x + (size_t)n * (64 * TV) + (size_t)t * 25;  // + c*TV + v

    const int lane = tid & 63, wv = tid >> 6;
    const int l15 = lane & 15, quad = lane >> 4;
    const int r32 = lane & 31, hi = lane >> 5;

    // ---- phase 0: x -> xs fp32 [v][c], fT bf16 [c][v] (v-pad zero) ----
    for (int i = tid; i < 1600; i += 256) {
        int c = i / 25, v = i - c * 25;
        float val = xb[c * TV + v];
        xs[v * 68 + c] = val;
        fT[c * 32 + v] = f2bf(val);
    }
    for (int i = tid; i < 448; i += 256) {
        int c = i / 7, v = 25 + (i % 7);
        fT[c * 32 + v] = 0;
    }
    __syncthreads();

    // ---- phase 1: LayerNorm over C -> yn (swizzled rows) ----
    {
        const float g = ln_g[lane], bt = ln_b[lane];
        for (int v = wv; v < 25; v += 4) {
            float f = xs[v * 68 + lane];
            float s = f, sq = f * f;
            #pragma unroll
            for (int off = 32; off > 0; off >>= 1) {
                s  += __shfl_xor(s, off, 64);
                sq += __shfl_xor(sq, off, 64);
            }
            float mu = s * (1.0f / 64.0f);
            float var = sq * (1.0f / 64.0f) - mu * mu;
            float rs = rsqrtf(var + EPSV);
            yn[v * 64 + (lane ^ ((v & 7) << 3))] = f2bf((f - mu) * rs * g + bt);
        }
    }
    __syncthreads();

    // ---- phase 2: qk = yn @ w_qk + b_qk (MFMA 16x16x32) -> qkb swizzled ----
    {
        bf16x8 a[2][2];
        #pragma unroll
        for (int mt = 0; mt < 2; mt++)
            #pragma unroll
            for (int ks = 0; ks < 2; ks++) {
                int row = mt * 16 + l15;
                a[mt][ks] = *(const bf16x8*)&yn[row * 64 + ((ks * 32 + quad * 8) ^ ((row & 7) << 3))];
            }
        #pragma unroll
        for (int i = 0; i < 2; i++) {
            int nt = wv * 2 + i;
            f32x4 acc0 = {0.f, 0.f, 0.f, 0.f};
            f32x4 acc1 = {0.f, 0.f, 0.f, 0.f};
            #pragma unroll
            for (int ks = 0; ks < 2; ks++) {
                bf16x8 bf = *(const bf16x8*)&wqk_f[(nt * 2 + ks) * 512 + lane * 8];
                acc0 = __builtin_amdgcn_mfma_f32_16x16x32_bf16(a[0][ks], bf, acc0, 0, 0, 0);
                acc1 = __builtin_amdgcn_mfma_f32_16x16x32_bf16(a[1][ks], bf, acc1, 0, 0, 0);
            }
            float bq = b_qk[nt * 16 + l15];
            int col = nt * 16 + l15;
            #pragma unroll
            for (int r = 0; r < 4; r++) {
                int u0 = quad * 4 + r;
                qkb[u0 * 128 + (col ^ ((u0 & 7) << 3))] = f2bf(acc0[r] + bq);
                int u1 = 16 + u0;
                if (u1 < 25) qkb[u1 * 128 + (col ^ ((u1 & 7) << 3))] = f2bf(acc1[r] + bq);
            }
        }
    }
    __syncthreads();

    // ---- phase 3: dots via MFMA 32x32x16 (K=8 padded; upper half-wave zeros) ----
    #pragma unroll
    for (int hh = 0; hh < 2; hh++) {
        int h = wv * 2 + hh;
        bf16x8 aq = {0,0,0,0,0,0,0,0};
        bf16x8 bk = {0,0,0,0,0,0,0,0};
        if (hi == 0) {
            aq = *(const bf16x8*)&qkb[r32 * 128 + ((h * 8) ^ ((r32 & 7) << 3))];
            bk = *(const bf16x8*)&qkb[r32 * 128 + ((64 + h * 8) ^ ((r32 & 7) << 3))];
        }
        f32x16 d = {0.f,0.f,0.f,0.f,0.f,0.f,0.f,0.f,0.f,0.f,0.f,0.f,0.f,0.f,0.f,0.f};
        d = __builtin_amdgcn_mfma_f32_32x32x16_bf16(aq, bk, d, 0, 0, 0);
        #pragma unroll
        for (int r = 0; r < 16; r++) {
            int u = (r & 3) + 8 * (r >> 2) + 4 * hi;
            if (u < 25) G[h * 1024 + u * 32 + r32] = f2bf(d[r] * SCALE);
        }
    }
    __syncthreads();

    // ---- phase 4: softmax over v, * topo, zero v-pad ----
    if (tid < 200) {
        int h = tid / 25, u = tid - h * 25;
        unsigned short* row = &G[h * 1024 + u * 32];
        const float* trow = &topo[h * 625 + u * 25];
        float e[25]; float m = -1e30f;
        #pragma unroll
        for (int v = 0; v < 25; v++) { e[v] = bf2f((short)row[v]); m = fmaxf(m, e[v]); }
        float s = 0.f;
        #pragma unroll
        for (int v = 0; v < 25; v++) { e[v] = __expf(e[v] - m); s += e[v]; }
        float inv = 1.0f / s;
        #pragma unroll
        for (int v = 0; v < 25; v++) row[v] = f2bf(e[v] * inv * trow[v]);
        #pragma unroll
        for (int v = 25; v < 32; v++) row[v] = 0;
    }
    __syncthreads();

    // ---- phases 5+6 in two 4-head passes through the 16 KB Z half-buffer ----
    bf16x8 bfT[4];
    #pragma unroll
    for (int nt = 0; nt < 4; nt++)
        bfT[nt] = *(const bf16x8*)&fT[(nt * 16 + l15) * 32 + quad * 8];

    f32x4 acc0 = {0.f, 0.f, 0.f, 0.f};
    f32x4 acc1 = {0.f, 0.f, 0.f, 0.f};
    #pragma unroll
    for (int p = 0; p < 2; p++) {
        int h = p * 4 + wv;                       // one head per wave per pass
        bf16x8 a0 = *(const bf16x8*)&G[h * 1024 + l15 * 32 + quad * 8];
        bf16x8 a1 = *(const bf16x8*)&G[h * 1024 + (16 + l15) * 32 + quad * 8];
        #pragma unroll
        for (int nt = 0; nt < 4; nt++) {
            f32x4 d0 = {0.f, 0.f, 0.f, 0.f};
            f32x4 d1 = {0.f, 0.f, 0.f, 0.f};
            d0 = __builtin_amdgcn_mfma_f32_16x16x32_bf16(a0, bfT[nt], d0, 0, 0, 0);
            d1 = __builtin_amdgcn_mfma_f32_16x16x32_bf16(a1, bfT[nt], d1, 0, 0, 0);
            int col = (h & 3) * 64 + nt * 16 + l15;
            #pragma unroll
            for (int r = 0; r < 4; r++) {
                int u0 = quad * 4 + r;
                Zh[u0 * 256 + (col ^ ((u0 & 7) << 3))] = f2bf(d0[r]);
                int u1 = 16 + u0;
                if (u1 < 25) Zh[u1 * 256 + (col ^ ((u1 & 7) << 3))] = f2bf(d1[r]);
            }
        }
        __syncthreads();   // Zh writes visible
        #pragma unroll
        for (int ksl = 0; ksl < 8; ksl++) {
            int ks = p * 8 + ksl;
            bf16x8 bw = *(const bf16x8*)&wcv_f[(wv * 16 + ks) * 512 + lane * 8];
            int colu = ksl * 32 + quad * 8;
            bf16x8 za = *(const bf16x8*)&Zh[l15 * 256 + (colu ^ ((l15 & 7) << 3))];
            bf16x8 zb = *(const bf16x8*)&Zh[(16 + l15) * 256 + (colu ^ (((16 + l15) & 7) << 3))];
            acc0 = __builtin_amdgcn_mfma_f32_16x16x32_bf16(za, bw, acc0, 0, 0, 0);
            acc1 = __builtin_amdgcn_mfma_f32_16x16x32_bf16(zb, bw, acc1, 0, 0, 0);
        }
        __syncthreads();   // phase-6 reads done before Zh reuse (next pass / outs)
    }

    // ---- epilogue: conv_b + BN -> outs (in Zh region) ----
    {
        int o = wv * 16 + l15;
        float gg = bn_g[o] * rsqrtf(bn_v[o] + EPSV);
        float bb = bn_b[o] - bn_m[o] * gg;
        float cb = 0.f;
        #pragma unroll
        for (int h = 0; h < 8; h++) cb += conv_b[h * 64 + o];
        #pragma unroll
        for (int r = 0; r < 4; r++) {
            int u0 = quad * 4 + r;
            outs[o * 26 + u0] = (acc0[r] + cb) * gg + bb;
            int u1 = 16 + u0;
            if (u1 < 25) outs[o * 26 + u1] = (acc1[r] + cb) * gg + bb;
        }
    }
    __syncthreads();

    // ---- residual + ReLU, coalesced store ----
    float* ob = out + (size_t)n * (64 * TV) + (size_t)t * 25;
    for (int i = tid; i < 1600; i += 256) {
        int o = i / 25, v = i - o * 25;
        ob[o * TV + v] = fmaxf(outs[o * 26 + v] + xb[o * TV + v], 0.f);
    }
}

extern "C" void kernel_launch(void* const* d_in, const int* in_sizes, int n_in,
                              void* d_out, int out_size, void* d_ws, size_t ws_size,
                              hipStream_t stream) {
    const float* x      = (const float*)d_in[0];
    const float* ln_g   = (const float*)d_in[1];
    const float* ln_b   = (const float*)d_in[2];
    const float* w_qk   = (const float*)d_in[3];
    const float* b_qk   = (const float*)d_in[4];
    const float* topo   = (const float*)d_in[5];
    const float* conv_w = (const float*)d_in[6];
    const float* conv_b = (const float*)d_in[7];
    const float* bn_g   = (const float*)d_in[8];
    const float* bn_b   = (const float*)d_in[9];
    const float* bn_m   = (const float*)d_in[10];
    const float* bn_v   = (const float*)d_in[11];
    float* outp = (float*)d_out;
    unsigned short* wsp = (unsigned short*)d_ws;

    hipLaunchKernelGGL(prep_kernel, dim3(160), dim3(256), 0, stream, w_qk, conv_w, wsp);
    hipLaunchKernelGGL(sagc_kernel, dim3(8192), dim3(256), 0, stream,
                       x, ln_g, ln_b, b_qk, topo, conv_b, bn_g, bn_b, bn_m, bn_v,
                       (const unsigned short*)wsp, outp);
}

// Round 5
// 189.117 us; speedup vs baseline: 4.9642x; 1.4482x over previous
//
#include <hip/hip_runtime.h>
#include <math.h>

#define SCALE 0.35355339059327373f
#define EPSV 1e-5f

typedef __attribute__((ext_vector_type(8))) short bf16x8;
typedef __attribute__((ext_vector_type(4))) float f32x4;
typedef __attribute__((ext_vector_type(16))) float f32x16;
typedef __attribute__((ext_vector_type(4))) int i32x4;
typedef __attribute__((ext_vector_type(2))) int i32x2;

static __device__ __forceinline__ unsigned short bfh(float f) {
    return (unsigned short)(__builtin_bit_cast(unsigned int, f) >> 16);
}
static __device__ __forceinline__ float bf2f(unsigned short s) {
    return __builtin_bit_cast(float, (unsigned int)s << 16);
}
static __device__ __forceinline__ int pack2(float lo, float hi) {
    return __builtin_amdgcn_perm(__builtin_bit_cast(unsigned int, hi),
                                 __builtin_bit_cast(unsigned int, lo), 0x07060302u);
}
#define LGKM0() __asm__ __volatile__("s_waitcnt lgkmcnt(0)" ::: "memory")

// ws layout: [0,8192) ushort wqk B-frags; [8192,40960) ushort W2ᵀ B-frags;
//            byte 81920: float bnA[64], bnB[64]
__global__ void prep_kernel(const float* __restrict__ w_qk,
                            const float* __restrict__ conv_w,
                            const float* __restrict__ conv_b,
                            const float* __restrict__ bn_g, const float* __restrict__ bn_b,
                            const float* __restrict__ bn_m, const float* __restrict__ bn_v,
                            unsigned short* __restrict__ ws) {
    int i = blockIdx.x * 256 + threadIdx.x;
    if (i < 8192) {
        // qk B-frag: frag(nt,ks): val = w_qk[k][n], k=ks*32+(l>>4)*8+j, n=nt*16+(l&15)
        int f = i >> 9, rem = i & 511, l = rem >> 3, j = rem & 7;
        int nt = f >> 1, ks = f & 1;
        int k = ks * 32 + (l >> 4) * 8 + j;
        int nn = nt * 16 + (l & 15);
        ws[i] = bfh(w_qk[k * 128 + nn]);
    } else if (i < 40960) {
        // W2ᵀ B-frag: frag(h,nt,ks): val = conv_w[h][o][c], c=ks*32+(l>>4)*8+j, o=nt*16+(l&15)
        int i2 = i - 8192;
        int g = i2 >> 9, rem = i2 & 511, l = rem >> 3, j = rem & 7;
        int h = g >> 3, nt = (g >> 1) & 3, ks = g & 1;
        int c = ks * 32 + (l >> 4) * 8 + j;
        int o = nt * 16 + (l & 15);
        ws[i] = bfh(conv_w[h * 4096 + o * 64 + c]);
    } else if (i < 41024) {
        int o = i - 40960;
        float gv = bn_g[o] * rsqrtf(bn_v[o] + EPSV);
        float bb = bn_b[o] - bn_m[o] * gv;
        float cb = 0.f;
        for (int h = 0; h < 8; h++) cb += conv_b[h * 64 + o];
        float* wsf = (float*)(ws + 40960);
        wsf[o] = gv;
        wsf[64 + o] = bb + cb * gv;
    }
}

// One WAVE per (n,t) tile; 4 waves/block; NO __syncthreads.
// Per-wave LDS (13312 B): [0,5120) xb16[32][72]u16 -> later FWT[64][40]u16
//                         [5120,8192) mus/rss (transient) then qbuf[32][24], kbuf@6656[32][24]
//                         [8192,13312) Gh[2][32][40]u16
__global__ __launch_bounds__(256, 3)
void sagc_kernel(const float* __restrict__ x,
                 const float* __restrict__ ln_g, const float* __restrict__ ln_b,
                 const float* __restrict__ b_qk,
                 const float* __restrict__ topo,
                 const unsigned short* __restrict__ ws,
                 float* __restrict__ out)
{
    __shared__ __align__(16) unsigned char smem[53248];
    const int tid = threadIdx.x;
    const int lane = tid & 63, wv = tid >> 6;
    const int l15 = lane & 15, quad = lane >> 4;
    const int r32 = lane & 31, hi = lane >> 5;

    unsigned char* my = smem + wv * 13312;
    unsigned short* xb16 = (unsigned short*)my;            // [32][72]
    unsigned short* FWT  = (unsigned short*)my;            // [64][40] (after xb16 dead)
    float*          mus  = (float*)(my + 5120);            // [32]+[32] (transient)
    float*          rss  = mus + 32;
    unsigned short* qbuf = (unsigned short*)(my + 5120);   // [32][24]
    unsigned short* kbuf = (unsigned short*)(my + 6656);   // [32][24]
    unsigned short* Gh   = (unsigned short*)(my + 8192);   // [2][32][40]

    const unsigned short* wqk = ws;
    const unsigned short* w2f = ws + 8192;
    const float* bnA = (const float*)(ws + 40960);
    const float* bnB = bnA + 64;

    const int tile = blockIdx.x * 4 + wv;
    const int n = tile >> 8, t = tile & 255;
    const float* xg = x + (size_t)n * 409600 + (size_t)t * 25;   // + c*6400 + v
    float* og = out + (size_t)n * 409600 + (size_t)t * 25;

    // ---- stage x -> xb16 [v][c] bf16 (rows 25..31 zeroed) ----
    #pragma unroll
    for (int it = 0; it < 25; it++) {
        int i = it * 64 + lane;
        int c = i / 25, v = i - c * 25;
        xb16[v * 72 + c] = bfh(xg[c * 6400 + v]);
    }
    #pragma unroll
    for (int k = 0; k < 8; k++) {
        int idx = k * 64 + lane;
        if (idx < 504) {
            int rr = idx / 72, cc = idx - rr * 72;
            xb16[(25 + rr) * 72 + cc] = 0;
        }
    }
    LGKM0();

    // ---- x A-frags + unpack + squares ----
    bf16x8 xa[2][2];
    #pragma unroll
    for (int mt = 0; mt < 2; mt++)
        #pragma unroll
        for (int ks = 0; ks < 2; ks++)
            xa[mt][ks] = *(const bf16x8*)&xb16[(mt * 16 + l15) * 72 + ks * 32 + quad * 8];

    float xf[2][2][8];
    bf16x8 sqf[2][2];
    #pragma unroll
    for (int mt = 0; mt < 2; mt++)
        #pragma unroll
        for (int ks = 0; ks < 2; ks++) {
            float s[8];
            #pragma unroll
            for (int j = 0; j < 8; j++) {
                xf[mt][ks][j] = bf2f((unsigned short)xa[mt][ks][j]);
                s[j] = xf[mt][ks][j] * xf[mt][ks][j];
            }
            i32x4 p;
            #pragma unroll
            for (int q = 0; q < 4; q++) p[q] = pack2(s[2 * q], s[2 * q + 1]);
            sqf[mt][ks] = __builtin_bit_cast(bf16x8, p);
        }

    // ---- LN stats via MFMA (B = ones * 1/64) ----
    {
        i32x4 ones_i = {0x3C803C80, 0x3C803C80, 0x3C803C80, 0x3C803C80};
        bf16x8 onesf = __builtin_bit_cast(bf16x8, ones_i);
        f32x4 z4 = {0.f, 0.f, 0.f, 0.f};
        f32x4 dmu[2], ds2[2];
        #pragma unroll
        for (int mt = 0; mt < 2; mt++) {
            dmu[mt] = __builtin_amdgcn_mfma_f32_16x16x32_bf16(xa[mt][0], onesf, z4, 0, 0, 0);
            dmu[mt] = __builtin_amdgcn_mfma_f32_16x16x32_bf16(xa[mt][1], onesf, dmu[mt], 0, 0, 0);
            ds2[mt] = __builtin_amdgcn_mfma_f32_16x16x32_bf16(sqf[mt][0], onesf, z4, 0, 0, 0);
            ds2[mt] = __builtin_amdgcn_mfma_f32_16x16x32_bf16(sqf[mt][1], onesf, ds2[mt], 0, 0, 0);
        }
        if (l15 == 0) {
            #pragma unroll
            for (int mt = 0; mt < 2; mt++)
                #pragma unroll
                for (int r = 0; r < 4; r++) {
                    int v = mt * 16 + quad * 4 + r;
                    float mu = dmu[mt][r];
                    float var = ds2[mt][r] - mu * mu;
                    mus[v] = mu;
                    rss[v] = rsqrtf(var + EPSV);
                }
        }
    }
    LGKM0();

    // ---- normalize in-register -> yn A-frags ----
    bf16x8 yna[2][2];
    {
        float muv[2] = {mus[l15], mus[16 + l15]};
        float rsv[2] = {rss[l15], rss[16 + l15]};
        #pragma unroll
        for (int ks = 0; ks < 2; ks++) {
            f32x4 ga = *(const f32x4*)&ln_g[ks * 32 + quad * 8];
            f32x4 gb = *(const f32x4*)&ln_g[ks * 32 + quad * 8 + 4];
            f32x4 ba = *(const f32x4*)&ln_b[ks * 32 + quad * 8];
            f32x4 bb = *(const f32x4*)&ln_b[ks * 32 + quad * 8 + 4];
            #pragma unroll
            for (int mt = 0; mt < 2; mt++) {
                float yv[8];
                #pragma unroll
                for (int j = 0; j < 8; j++) {
                    float g = (j < 4) ? ga[j] : gb[j - 4];
                    float bt = (j < 4) ? ba[j] : bb[j - 4];
                    yv[j] = (xf[mt][ks][j] - muv[mt]) * rsv[mt] * g + bt;
                }
                i32x4 p;
                #pragma unroll
                for (int q = 0; q < 4; q++) p[q] = pack2(yv[2 * q], yv[2 * q + 1]);
                yna[mt][ks] = __builtin_bit_cast(bf16x8, p);
            }
        }
    }

    // ---- accumulators for out = sum_h G_h @ FW_h ----
    f32x4 acc[2][4];
    #pragma unroll
    for (int mt = 0; mt < 2; mt++)
        #pragma unroll
        for (int nt = 0; nt < 4; nt++)
            acc[mt][nt] = (f32x4){0.f, 0.f, 0.f, 0.f};

    const f32x4 z4 = {0.f, 0.f, 0.f, 0.f};
    const bf16x8 z8 = {0, 0, 0, 0, 0, 0, 0, 0};

    // ---- head-pair loop ----
    for (int hp = 0; hp < 4; hp++) {
        // qk tiles: q-tile nt=hp (SCALE folded), k-tile nt=4+hp
        #pragma unroll
        for (int tsel = 0; tsel < 2; tsel++) {
            int nt = tsel ? (4 + hp) : hp;
            bf16x8 b0 = *(const bf16x8*)&wqk[(nt * 2 + 0) * 512 + lane * 8];
            bf16x8 b1 = *(const bf16x8*)&wqk[(nt * 2 + 1) * 512 + lane * 8];
            float bias = b_qk[(tsel ? 64 : 0) + hp * 16 + l15];
            unsigned short* buf = tsel ? kbuf : qbuf;
            #pragma unroll
            for (int mt = 0; mt < 2; mt++) {
                f32x4 d = __builtin_amdgcn_mfma_f32_16x16x32_bf16(yna[mt][0], b0, z4, 0, 0, 0);
                d = __builtin_amdgcn_mfma_f32_16x16x32_bf16(yna[mt][1], b1, d, 0, 0, 0);
                #pragma unroll
                for (int r = 0; r < 4; r++) {
                    int u = mt * 16 + quad * 4 + r;
                    if (u < 25) {
                        float val = d[r] + bias;
                        if (!tsel) val *= SCALE;
                        buf[u * 24 + l15] = bfh(val);
                    }
                }
            }
        }
        LGKM0();

        // dots: per head one 32x32x16 MFMA (K=8 real + 8 zero)
        #pragma unroll
        for (int hh = 0; hh < 2; hh++) {
            bf16x8 aq = z8, bk = z8;
            if (hi == 0) {
                aq = *(const bf16x8*)&qbuf[r32 * 24 + hh * 8];
                bk = *(const bf16x8*)&kbuf[r32 * 24 + hh * 8];
            }
            f32x16 dd = {0.f,0.f,0.f,0.f,0.f,0.f,0.f,0.f,0.f,0.f,0.f,0.f,0.f,0.f,0.f,0.f};
            dd = __builtin_amdgcn_mfma_f32_32x32x16_bf16(aq, bk, dd, 0, 0, 0);
            #pragma unroll
            for (int r = 0; r < 16; r++) {
                int u = (r & 3) + 8 * (r >> 2) + 4 * hi;
                if (u < 25) Gh[hh * 1280 + u * 40 + r32] = bfh(dd[r]);
            }
        }
        LGKM0();

        // softmax * topo (50 active lanes: 2 heads x 25 rows), in-place, pad cols zeroed
        {
            int smh = lane >> 5, su = lane & 31;
            if (su < 25) {
                unsigned short* rowp = Gh + smh * 1280 + su * 40;
                i32x4 ra = *(const i32x4*)rowp;
                i32x4 rb = *(const i32x4*)(rowp + 8);
                i32x4 rc = *(const i32x4*)(rowp + 16);
                float f[25];
                #pragma unroll
                for (int w = 0; w < 4; w++) {
                    f[2 * w]      = __builtin_bit_cast(float, (unsigned)ra[w] << 16);
                    f[2 * w + 1]  = __builtin_bit_cast(float, (unsigned)ra[w] & 0xFFFF0000u);
                    f[8 + 2 * w]  = __builtin_bit_cast(float, (unsigned)rb[w] << 16);
                    f[9 + 2 * w]  = __builtin_bit_cast(float, (unsigned)rb[w] & 0xFFFF0000u);
                    f[16 + 2 * w] = __builtin_bit_cast(float, (unsigned)rc[w] << 16);
                    f[17 + 2 * w] = __builtin_bit_cast(float, (unsigned)rc[w] & 0xFFFF0000u);
                }
                f[24] = bf2f(rowp[24]);
                float m = f[0];
                #pragma unroll
                for (int v = 1; v < 25; v++) m = fmaxf(m, f[v]);
                float s = 0.f;
                #pragma unroll
                for (int v = 0; v < 25; v++) { f[v] = __expf(f[v] - m); s += f[v]; }
                float inv = 1.0f / s;
                const float* tp = topo + (hp * 2 + smh) * 625 + su * 25;
                #pragma unroll
                for (int v = 0; v < 25; v++) f[v] = f[v] * inv * tp[v];
                int d[16];
                #pragma unroll
                for (int p = 0; p < 12; p++) d[p] = pack2(f[2 * p], f[2 * p + 1]);
                d[12] = pack2(f[24], 0.f);
                d[13] = 0; d[14] = 0; d[15] = 0;
                *(i32x4*)rowp        = (i32x4){d[0], d[1], d[2], d[3]};
                *(i32x4*)(rowp + 8)  = (i32x4){d[4], d[5], d[6], d[7]};
                *(i32x4*)(rowp + 16) = (i32x4){d[8], d[9], d[10], d[11]};
                *(i32x4*)(rowp + 24) = (i32x4){d[12], d[13], d[14], d[15]};
            }
        }
        LGKM0();

        // per head: FW_h = feat @ W2ᵀ_h (D-quads -> FWT b64), then acc += G_h @ FW_h
        #pragma unroll
        for (int hh = 0; hh < 2; hh++) {
            int h = hp * 2 + hh;
            #pragma unroll
            for (int nt = 0; nt < 4; nt++) {
                bf16x8 w0 = *(const bf16x8*)&w2f[((h * 4 + nt) * 2 + 0) * 512 + lane * 8];
                bf16x8 w1 = *(const bf16x8*)&w2f[((h * 4 + nt) * 2 + 1) * 512 + lane * 8];
                f32x4 dw0 = __builtin_amdgcn_mfma_f32_16x16x32_bf16(xa[0][0], w0, z4, 0, 0, 0);
                dw0 = __builtin_amdgcn_mfma_f32_16x16x32_bf16(xa[0][1], w1, dw0, 0, 0, 0);
                f32x4 dw1 = __builtin_amdgcn_mfma_f32_16x16x32_bf16(xa[1][0], w0, z4, 0, 0, 0);
                dw1 = __builtin_amdgcn_mfma_f32_16x16x32_bf16(xa[1][1], w1, dw1, 0, 0, 0);
                int o = nt * 16 + l15;
                i32x2 q0 = {pack2(dw0[0], dw0[1]), pack2(dw0[2], dw0[3])};
                i32x2 q1 = {pack2(dw1[0], dw1[1]), pack2(dw1[2], dw1[3])};
                *(i32x2*)&FWT[o * 40 + quad * 4] = q0;
                *(i32x2*)&FWT[o * 40 + 16 + quad * 4] = q1;
            }
            LGKM0();
            bf16x8 ag0 = *(const bf16x8*)&Gh[hh * 1280 + l15 * 40 + quad * 8];
            bf16x8 ag1 = *(const bf16x8*)&Gh[hh * 1280 + (16 + l15) * 40 + quad * 8];
            #pragma unroll
            for (int nt = 0; nt < 4; nt++) {
                bf16x8 br = *(const bf16x8*)&FWT[(nt * 16 + l15) * 40 + quad * 8];
                acc[0][nt] = __builtin_amdgcn_mfma_f32_16x16x32_bf16(ag0, br, acc[0][nt], 0, 0, 0);
                acc[1][nt] = __builtin_amdgcn_mfma_f32_16x16x32_bf16(ag1, br, acc[1][nt], 0, 0, 0);
            }
        }
    }

    // ---- epilogue: BN + residual + ReLU, direct global store ----
    #pragma unroll
    for (int nt = 0; nt < 4; nt++) {
        int o = nt * 16 + l15;
        float gA = bnA[o], gB = bnB[o];
        #pragma unroll
        for (int mt = 0; mt < 2; mt++) {
            int ub = mt * 16 + quad * 4;
            #pragma unroll
            for (int r = 0; r < 4; r++) {
                int u = ub + r;
                if (u < 25) {
                    float val = acc[mt][nt][r] * gA + gB + xg[o * 6400 + u];
                    og[o * 6400 + u] = fmaxf(val, 0.f);
                }
            }
        }
    }
}

extern "C" void kernel_launch(void* const* d_in, const int* in_sizes, int n_in,
                              void* d_out, int out_size, void* d_ws, size_t ws_size,
                              hipStream_t stream) {
    const float* x      = (const float*)d_in[0];
    const float* ln_g   = (const float*)d_in[1];
    const float* ln_b   = (const float*)d_in[2];
    const float* w_qk   = (const float*)d_in[3];
    const float* b_qk   = (const float*)d_in[4];
    const float* topo   = (const float*)d_in[5];
    const float* conv_w = (const float*)d_in[6];
    const float* conv_b = (const float*)d_in[7];
    const float* bn_g   = (const float*)d_in[8];
    const float* bn_b   = (const float*)d_in[9];
    const float* bn_m   = (const float*)d_in[10];
    const float* bn_v   = (const float*)d_in[11];
    float* outp = (float*)d_out;
    unsigned short* wsp = (unsigned short*)d_ws;

    hipLaunchKernelGGL(prep_kernel, dim3(161), dim3(256), 0, stream,
                       w_qk, conv_w, conv_b, bn_g, bn_b, bn_m, bn_v, wsp);
    hipLaunchKernelGGL(sagc_kernel, dim3(2048), dim3(256), 0, stream,
                       x, ln_g, ln_b, b_qk, topo, (const unsigned short*)wsp, outp);
}